// Round 1
// baseline (107.301 us; speedup 1.0000x reference)
//
#include <hip/hip_runtime.h>

// DropDim: out[b,t,d] = h[b,t,d] * (mask[b,d] != 0)
// B=16, T=4096, D=1024. h: f32. mask: bernoulli keep-mask (passed as int32).
// Memory-bound streaming op: 256 MiB read + 256 MiB write, mask is 64 KiB
// (cache-resident). Roofline ~85us at 6.3 TB/s achievable.

#define BB 16
#define TT 4096
#define DD 1024
// T*D/4 = 4096*256 = 2^20 float4-chunks per batch sample
#define TD4_SHIFT 20
#define D4_MASK 255   // (D/4 - 1)

__global__ void __launch_bounds__(256)
DropDim_kernel(const float4* __restrict__ h,
               const int4* __restrict__ mask,
               float4* __restrict__ out,
               long n4) {
    long stride = (long)gridDim.x * blockDim.x;
    for (long i = (long)blockIdx.x * blockDim.x + threadIdx.x; i < n4; i += stride) {
        int b  = (int)(i >> TD4_SHIFT);   // batch index
        int d4 = (int)(i & D4_MASK);      // float4-chunk within the D axis
        float4 v = h[i];
        int4 m = mask[b * (DD / 4) + d4]; // 64 KiB total -> L1/L2 hit
        v.x = m.x ? v.x : 0.0f;
        v.y = m.y ? v.y : 0.0f;
        v.z = m.z ? v.z : 0.0f;
        v.w = m.w ? v.w : 0.0f;
        out[i] = v;
    }
}

extern "C" void kernel_launch(void* const* d_in, const int* in_sizes, int n_in,
                              void* d_out, int out_size, void* d_ws, size_t ws_size,
                              hipStream_t stream) {
    const float4* h    = (const float4*)d_in[0];
    const int4*   mask = (const int4*)d_in[1];
    float4*       out  = (float4*)d_out;

    long n4 = (long)in_sizes[0] / 4;   // 16,777,216 float4 chunks

    const int block = 256;
    const int grid  = 2048;  // 256 CUs x 8 blocks; grid-stride covers the rest

    DropDim_kernel<<<grid, block, 0, stream>>>(h, mask, out, n4);
}